// Round 4
// baseline (4090.300 us; speedup 1.0000x reference)
//
#include <hip/hip_runtime.h>
#include <cmath>

// GRU scan, T=128 B=512 D=H=512, split-f16 MFMA (f32-accurate):
//   v = hi + lo/2048 ; a*b ~= ah*bh + (ah*bl + al*bh)/2048
// Phase 0: transpose+split weights -> WT_hi/WT_lo [3072][512] in d_ws.
// Phase 1: gi = x@Wi + bi for all steps (one big GEMM into d_ws).
// Phase 2: 128 sequential step kernels: h@[Wh_r|Wh_z|Wh_n] + gates.
//   B-fragments read DIRECT from global (K-major rows, L2-resident);
//   only h is staged in LDS (hi/lo planes, stride 520 halfs -> 2-way banks);
//   ONE barrier per kernel; gi/heff prefetched at top.
// d_out = [hT (B*H) | ys (T*B*H)]; h_prev for step t read from ys[t-1].

#define T_STEPS 128
#define B_SZ 512
#define HD 512

typedef __attribute__((ext_vector_type(8))) _Float16 f16x8;
typedef __attribute__((ext_vector_type(4))) float f32x4;

#define MFMA16(a, b, c) __builtin_amdgcn_mfma_f32_16x16x32_f16((a), (b), (c), 0, 0, 0)

__device__ __forceinline__ float sigf_(float x) { return 1.0f / (1.0f + __expf(-x)); }
__device__ __forceinline__ float tanhf_(float x) { return 1.0f - 2.0f / (__expf(2.0f * x) + 1.0f); }

// ---------------------------------------------------------------------------
// Phase 0: transpose + split weights. WT[n][k]: n<1536 -> Wi col n;
// n>=1536: m=n-1536, g=m>>9, c=m&511: g<2 -> Wh_rz[k][g*512+c]; g==2 -> Wh_n[k][c]
// ---------------------------------------------------------------------------
__global__ __launch_bounds__(256) void conv_w(
    const float* __restrict__ Wi, const float* __restrict__ Wh_rz,
    const float* __restrict__ Wh_n,
    _Float16* __restrict__ WT_hi, _Float16* __restrict__ WT_lo)
{
    __shared__ float Tl[64][65];
    const int tid = threadIdx.x;
    const int k0 = blockIdx.x * 64;
    const int n0 = blockIdx.y * 64;

    const float* base;
    int stride;
    if (n0 < 1536) { base = Wi + n0; stride = 1536; }
    else {
        int m = n0 - 1536, g = m >> 9, c = m & 511;
        if (g < 2) { base = Wh_rz + g * 512 + c; stride = 1024; }
        else       { base = Wh_n + c;            stride = 512; }
    }

    #pragma unroll
    for (int p = 0; p < 4; ++p) {
        int kr = p * 16 + (tid >> 4);
        int nc = (tid & 15) * 4;
        float4 v = *(const float4*)(base + (size_t)(k0 + kr) * stride + nc);
        Tl[kr][nc + 0] = v.x; Tl[kr][nc + 1] = v.y;
        Tl[kr][nc + 2] = v.z; Tl[kr][nc + 3] = v.w;
    }
    __syncthreads();

    const int nr  = tid >> 2;
    const int kc0 = (tid & 3) * 16;
    f16x8 h0v, h1v, l0v, l1v;
    #pragma unroll
    for (int j = 0; j < 16; ++j) {
        float v = Tl[kc0 + j][nr];
        _Float16 th = (_Float16)v;
        _Float16 tl = (_Float16)((v - (float)th) * 2048.0f);
        if (j < 8) { h0v[j] = th; l0v[j] = tl; }
        else       { h1v[j - 8] = th; l1v[j - 8] = tl; }
    }
    size_t o = (size_t)(n0 + nr) * 512 + k0 + kc0;
    *(f16x8*)(WT_hi + o)     = h0v;
    *(f16x8*)(WT_hi + o + 8) = h1v;
    *(f16x8*)(WT_lo + o)     = l0v;
    *(f16x8*)(WT_lo + o + 8) = l1v;
}

// ---------------------------------------------------------------------------
// Phase 1: gi = x @ Wi + bi.  grid (24 n-tiles, R/64 m-tiles), 4 waves.
// BM=64, BN=64, K=512 single-stage. A (x) in LDS hi/lo [64][520]; B from global.
// Wave w owns m rows w*16..w*16+15, all 64 n cols (4 j-frags).
// ---------------------------------------------------------------------------
__global__ __launch_bounds__(256, 1) void gi_gemm(
    const float* __restrict__ x,        // [R][512]
    const _Float16* __restrict__ WT_hi,
    const _Float16* __restrict__ WT_lo,
    const float* __restrict__ bi,       // [1536]
    float* __restrict__ gi)             // [R][1536]
{
    __shared__ __align__(16) _Float16 Ah[64 * 520];
    __shared__ __align__(16) _Float16 Al[64 * 520];

    const int tid = threadIdx.x;
    const int n0 = blockIdx.x * 64;
    const int m0 = blockIdx.y * 64;
    const int l = tid & 63, w = tid >> 6;
    const int lr = l & 15, lkq = l >> 4, lk = lkq * 8;

    // ---- stage x (64x512 f32 -> split f16), coalesced 2KB per wave-row ----
    #pragma unroll
    for (int i = 0; i < 16; ++i) {
        const int row = i * 4 + w;
        const int col = l * 8;
        const float* p = x + (size_t)(m0 + row) * 512 + col;
        float4 v0 = *(const float4*)p, v1 = *(const float4*)(p + 4);
        float xf[8] = {v0.x, v0.y, v0.z, v0.w, v1.x, v1.y, v1.z, v1.w};
        f16x8 hh, ll;
        #pragma unroll
        for (int jq = 0; jq < 8; ++jq) {
            float v = xf[jq];
            _Float16 th = (_Float16)v;
            hh[jq] = th; ll[jq] = (_Float16)((v - (float)th) * 2048.0f);
        }
        *(f16x8*)&Ah[row * 520 + col] = hh;
        *(f16x8*)&Al[row * 520 + col] = ll;
    }
    __syncthreads();

    // ---- B pointers (direct global, K-major rows) ----
    const _Float16* bhp[4];
    const _Float16* blp[4];
    #pragma unroll
    for (int jf = 0; jf < 4; ++jf) {
        const int c = n0 + jf * 16 + lr;
        bhp[jf] = WT_hi + (size_t)c * 512 + lk;
        blp[jf] = WT_lo + (size_t)c * 512 + lk;
    }

    f32x4 am[4], ac[4];
    #pragma unroll
    for (int jf = 0; jf < 4; ++jf) { am[jf] = (f32x4){0,0,0,0}; ac[jf] = (f32x4){0,0,0,0}; }

    f16x8 bhc[4], blc[4], bhn_[4], bln_[4];
    #pragma unroll
    for (int jf = 0; jf < 4; ++jf) {
        bhc[jf] = *(const f16x8*)bhp[jf];
        blc[jf] = *(const f16x8*)blp[jf];
    }

    const int arow = (w * 16 + lr) * 520;
    #pragma unroll
    for (int kk = 0; kk < 16; ++kk) {
        if (kk < 15) {
            const int o = (kk + 1) * 32;
            #pragma unroll
            for (int jf = 0; jf < 4; ++jf) {
                bhn_[jf] = *(const f16x8*)(bhp[jf] + o);
                bln_[jf] = *(const f16x8*)(blp[jf] + o);
            }
        }
        f16x8 ah = *(const f16x8*)&Ah[arow + kk * 32 + lk];
        f16x8 al = *(const f16x8*)&Al[arow + kk * 32 + lk];
        #pragma unroll
        for (int jf = 0; jf < 4; ++jf) {
            am[jf] = MFMA16(ah, bhc[jf], am[jf]);
            ac[jf] = MFMA16(ah, blc[jf], ac[jf]);
            ac[jf] = MFMA16(al, bhc[jf], ac[jf]);
        }
        if (kk < 15) {
            #pragma unroll
            for (int jf = 0; jf < 4; ++jf) { bhc[jf] = bhn_[jf]; blc[jf] = bln_[jf]; }
        }
    }

    const float inv = 1.0f / 2048.0f;
    #pragma unroll
    for (int jf = 0; jf < 4; ++jf) {
        const int col = n0 + jf * 16 + lr;
        const float bv = bi[col];
        #pragma unroll
        for (int i = 0; i < 4; ++i) {
            const int row = m0 + w * 16 + lkq * 4 + i;
            gi[(size_t)row * 1536 + col] = am[jf][i] + ac[jf][i] * inv + bv;
        }
    }
}

// ---------------------------------------------------------------------------
// Phase 2: step kernel. grid (16 j-tiles, 8 m-tiles), 4 waves (mh=w>>1, jh=w&1).
// Tile 64m x 32j, K=512 single-stage, B direct from global, one barrier.
// ---------------------------------------------------------------------------
__global__ __launch_bounds__(256, 1) void gru_step_h(
    const int*   __restrict__ rst,      // [B]
    const float* __restrict__ hsrc,     // [B][512]
    const _Float16* __restrict__ WT_hi, // hidden rows at 1536+
    const _Float16* __restrict__ WT_lo,
    const float* __restrict__ gi_t,     // [512][1536]
    const float* __restrict__ bh_n,     // [512]
    float* __restrict__ hdst,
    float* __restrict__ hT_out)
{
    __shared__ __align__(16) _Float16 Ah[64 * 520];
    __shared__ __align__(16) _Float16 Al[64 * 520];

    const int tid = threadIdx.x;
    const int j0 = blockIdx.x * 32;
    const int m0 = blockIdx.y * 64;
    const int l = tid & 63, w = tid >> 6;
    const int mh = w >> 1, jh = w & 1;
    const int lr = l & 15, lkq = l >> 4, lk = lkq * 8;
    const int j = j0 + jh * 16 + lr;

    // ---- prefetch epilogue operands (latency hides under the GEMM) ----
    float gi_pre[2][3][4];
    float h_pre[2][4];
    #pragma unroll
    for (int fm = 0; fm < 2; ++fm)
        #pragma unroll
        for (int i = 0; i < 4; ++i) {
            const int row = m0 + mh * 32 + fm * 16 + lkq * 4 + i;
            const size_t gb = (size_t)row * 1536 + j;
            gi_pre[fm][0][i] = gi_t[gb];
            gi_pre[fm][1][i] = gi_t[gb + 512];
            gi_pre[fm][2][i] = gi_t[gb + 1024];
            h_pre[fm][i] = hsrc[(size_t)row * 512 + j];
        }

    // ---- stage h (64x512 f32 -> split f16, reset-masked) ----
    #pragma unroll
    for (int i = 0; i < 16; ++i) {
        const int row = i * 4 + w;
        const int col = l * 8;
        const bool rm = (rst[m0 + row] != 0);
        const float* p = hsrc + (size_t)(m0 + row) * 512 + col;
        float4 v0 = *(const float4*)p, v1 = *(const float4*)(p + 4);
        if (rm) { v0 = make_float4(0,0,0,0); v1 = make_float4(0,0,0,0); }
        float hf[8] = {v0.x, v0.y, v0.z, v0.w, v1.x, v1.y, v1.z, v1.w};
        f16x8 hh, ll;
        #pragma unroll
        for (int jq = 0; jq < 8; ++jq) {
            float v = hf[jq];
            _Float16 th = (_Float16)v;
            hh[jq] = th; ll[jq] = (_Float16)((v - (float)th) * 2048.0f);
        }
        *(f16x8*)&Ah[row * 520 + col] = hh;
        *(f16x8*)&Al[row * 520 + col] = ll;
    }
    __syncthreads();

    // ---- B pointers: gate g row base = 1536 + g*512 + j ----
    const _Float16* bhp = WT_hi + (size_t)(1536 + j) * 512 + lk;
    const _Float16* blp = WT_lo + (size_t)(1536 + j) * 512 + lk;
    constexpr int GS = 512 * 512;   // gate stride in elements

    f32x4 aRm[2], aRc[2], aZm[2], aZc[2], aNm[2], aNc[2];
    #pragma unroll
    for (int fm = 0; fm < 2; ++fm) {
        aRm[fm] = (f32x4){0,0,0,0}; aRc[fm] = (f32x4){0,0,0,0};
        aZm[fm] = (f32x4){0,0,0,0}; aZc[fm] = (f32x4){0,0,0,0};
        aNm[fm] = (f32x4){0,0,0,0}; aNc[fm] = (f32x4){0,0,0,0};
    }

    f16x8 bc[6], bn_[6];
    bc[0] = *(const f16x8*)(bhp);
    bc[1] = *(const f16x8*)(bhp + GS);
    bc[2] = *(const f16x8*)(bhp + 2 * GS);
    bc[3] = *(const f16x8*)(blp);
    bc[4] = *(const f16x8*)(blp + GS);
    bc[5] = *(const f16x8*)(blp + 2 * GS);

    #pragma unroll
    for (int kk = 0; kk < 16; ++kk) {
        if (kk < 15) {
            const int o = (kk + 1) * 32;
            bn_[0] = *(const f16x8*)(bhp + o);
            bn_[1] = *(const f16x8*)(bhp + GS + o);
            bn_[2] = *(const f16x8*)(bhp + 2 * GS + o);
            bn_[3] = *(const f16x8*)(blp + o);
            bn_[4] = *(const f16x8*)(blp + GS + o);
            bn_[5] = *(const f16x8*)(blp + 2 * GS + o);
        }
        #pragma unroll
        for (int fm = 0; fm < 2; ++fm) {
            const int ar = (mh * 32 + fm * 16 + lr) * 520 + kk * 32 + lk;
            f16x8 ah = *(const f16x8*)&Ah[ar];
            f16x8 al = *(const f16x8*)&Al[ar];
            aRm[fm] = MFMA16(ah, bc[0], aRm[fm]);
            aRc[fm] = MFMA16(ah, bc[3], aRc[fm]);
            aRc[fm] = MFMA16(al, bc[0], aRc[fm]);
            aZm[fm] = MFMA16(ah, bc[1], aZm[fm]);
            aZc[fm] = MFMA16(ah, bc[4], aZc[fm]);
            aZc[fm] = MFMA16(al, bc[1], aZc[fm]);
            aNm[fm] = MFMA16(ah, bc[2], aNm[fm]);
            aNc[fm] = MFMA16(ah, bc[5], aNc[fm]);
            aNc[fm] = MFMA16(al, bc[2], aNc[fm]);
        }
        if (kk < 15) {
            #pragma unroll
            for (int q = 0; q < 6; ++q) bc[q] = bn_[q];
        }
    }

    // ---- epilogue: gates ----
    const float bhn = bh_n[j];
    const float inv = 1.0f / 2048.0f;
    #pragma unroll
    for (int fm = 0; fm < 2; ++fm)
        #pragma unroll
        for (int i = 0; i < 4; ++i) {
            const int row = m0 + mh * 32 + fm * 16 + lkq * 4 + i;
            const bool rm = (rst[row] != 0);
            const float heff = rm ? 0.f : h_pre[fm][i];
            const float r = sigf_(gi_pre[fm][0][i] + aRm[fm][i] + aRc[fm][i] * inv);
            const float z = sigf_(gi_pre[fm][1][i] + aZm[fm][i] + aZc[fm][i] * inv);
            const float n = tanhf_(gi_pre[fm][2][i] + r * (aNm[fm][i] + aNc[fm][i] * inv + bhn));
            const float hv = (1.f - z) * n + z * heff;
            hdst[(size_t)row * 512 + j] = hv;
            if (hT_out) hT_out[(size_t)row * 512 + j] = hv;
        }
}

// ---------------------------------------------------------------------------
// Fallback: pure-f32 step kernel (used only if d_ws is too small).
// ---------------------------------------------------------------------------
constexpr int BM_F = 32, BN_F = 32, BK_F = 32;
constexpr int LDT = BM_F + 4;

__global__ __launch_bounds__(256, 1) void gru_step_f32(
    const float* __restrict__ x, const int* __restrict__ rst,
    const float* __restrict__ h_prev, const float* __restrict__ Wi,
    const float* __restrict__ bi, const float* __restrict__ Wh_rz,
    const float* __restrict__ Wh_n, const float* __restrict__ bh_n,
    float* __restrict__ h_out, float* __restrict__ hT_out)
{
    __shared__ float xs[BK_F][LDT];
    __shared__ float hs[BK_F][LDT];
    __shared__ float wt[6][BK_F][LDT];

    const int tid = threadIdx.x;
    const int bm0 = blockIdx.x * BM_F;
    const int jn0 = blockIdx.y * BN_F;
    const int lrw = tid >> 3;
    const int lcw = (tid & 7) << 2;
    const int ty = tid >> 4, tx = tid & 15;
    const int row0 = 2 * ty, col0 = 2 * tx;

    float aR[2][2] = {{0,0},{0,0}}, aZ[2][2] = {{0,0},{0,0}}, aN[2][2] = {{0,0},{0,0}};
    float hR[2][2] = {{0,0},{0,0}}, hZ[2][2] = {{0,0},{0,0}}, hN[2][2] = {{0,0},{0,0}};

    const int ldrow = bm0 + lrw;
    const bool rmaskld = (rst[ldrow] != 0);
    const float* xrow = x + (size_t)ldrow * 512;
    const float* hrow = h_prev + (size_t)ldrow * 512;

    for (int k0 = 0; k0 < 512; k0 += BK_F) {
        float4 xv = *(const float4*)(xrow + k0 + lcw);
        float4 hv = *(const float4*)(hrow + k0 + lcw);
        if (rmaskld) { hv.x = hv.y = hv.z = hv.w = 0.f; }
        const float* wi_row = Wi + (size_t)(k0 + lrw) * 1536;
        const float* wh_row = Wh_rz + (size_t)(k0 + lrw) * 1024;
        float4 w0v = *(const float4*)(wi_row + jn0 + lcw);
        float4 w1v = *(const float4*)(wi_row + 512 + jn0 + lcw);
        float4 w2v = *(const float4*)(wi_row + 1024 + jn0 + lcw);
        float4 w3v = *(const float4*)(wh_row + jn0 + lcw);
        float4 w4v = *(const float4*)(wh_row + 512 + jn0 + lcw);
        float4 w5v = *(const float4*)(Wh_n + (size_t)(k0 + lrw) * 512 + jn0 + lcw);
        __syncthreads();
        xs[lcw+0][lrw]=xv.x; xs[lcw+1][lrw]=xv.y; xs[lcw+2][lrw]=xv.z; xs[lcw+3][lrw]=xv.w;
        hs[lcw+0][lrw]=hv.x; hs[lcw+1][lrw]=hv.y; hs[lcw+2][lrw]=hv.z; hs[lcw+3][lrw]=hv.w;
        *(float4*)&wt[0][lrw][lcw] = w0v; *(float4*)&wt[1][lrw][lcw] = w1v;
        *(float4*)&wt[2][lrw][lcw] = w2v; *(float4*)&wt[3][lrw][lcw] = w3v;
        *(float4*)&wt[4][lrw][lcw] = w4v; *(float4*)&wt[5][lrw][lcw] = w5v;
        __syncthreads();
        #pragma unroll
        for (int kk = 0; kk < BK_F; ++kk) {
            float2 xa = *(const float2*)&xs[kk][row0];
            float2 ha = *(const float2*)&hs[kk][row0];
            float2 w0 = *(const float2*)&wt[0][kk][col0];
            float2 w1 = *(const float2*)&wt[1][kk][col0];
            float2 w2 = *(const float2*)&wt[2][kk][col0];
            float2 w3 = *(const float2*)&wt[3][kk][col0];
            float2 w4 = *(const float2*)&wt[4][kk][col0];
            float2 w5 = *(const float2*)&wt[5][kk][col0];
            aR[0][0]=fmaf(xa.x,w0.x,aR[0][0]); aR[0][1]=fmaf(xa.x,w0.y,aR[0][1]);
            aR[1][0]=fmaf(xa.y,w0.x,aR[1][0]); aR[1][1]=fmaf(xa.y,w0.y,aR[1][1]);
            aZ[0][0]=fmaf(xa.x,w1.x,aZ[0][0]); aZ[0][1]=fmaf(xa.x,w1.y,aZ[0][1]);
            aZ[1][0]=fmaf(xa.y,w1.x,aZ[1][0]); aZ[1][1]=fmaf(xa.y,w1.y,aZ[1][1]);
            aN[0][0]=fmaf(xa.x,w2.x,aN[0][0]); aN[0][1]=fmaf(xa.x,w2.y,aN[0][1]);
            aN[1][0]=fmaf(xa.y,w2.x,aN[1][0]); aN[1][1]=fmaf(xa.y,w2.y,aN[1][1]);
            hR[0][0]=fmaf(ha.x,w3.x,hR[0][0]); hR[0][1]=fmaf(ha.x,w3.y,hR[0][1]);
            hR[1][0]=fmaf(ha.y,w3.x,hR[1][0]); hR[1][1]=fmaf(ha.y,w3.y,hR[1][1]);
            hZ[0][0]=fmaf(ha.x,w4.x,hZ[0][0]); hZ[0][1]=fmaf(ha.x,w4.y,hZ[0][1]);
            hZ[1][0]=fmaf(ha.y,w4.x,hZ[1][0]); hZ[1][1]=fmaf(ha.y,w4.y,hZ[1][1]);
            hN[0][0]=fmaf(ha.x,w5.x,hN[0][0]); hN[0][1]=fmaf(ha.x,w5.y,hN[0][1]);
            hN[1][0]=fmaf(ha.y,w5.x,hN[1][0]); hN[1][1]=fmaf(ha.y,w5.y,hN[1][1]);
        }
    }
    #pragma unroll
    for (int ii = 0; ii < 2; ++ii) {
        const int b = bm0 + row0 + ii;
        const bool rm = (rst[b] != 0);
        #pragma unroll
        for (int jj = 0; jj < 2; ++jj) {
            const int jn = jn0 + col0 + jj;
            const float heff = rm ? 0.f : h_prev[(size_t)b * 512 + jn];
            const float r = sigf_(aR[ii][jj] + bi[jn] + hR[ii][jj]);
            const float z = sigf_(aZ[ii][jj] + bi[512 + jn] + hZ[ii][jj]);
            const float n = tanhf(aN[ii][jj] + bi[1024 + jn] + r * (hN[ii][jj] + bh_n[jn]));
            const float v = (1.f - z) * n + z * heff;
            h_out[(size_t)b * 512 + jn] = v;
            if (hT_out) hT_out[(size_t)b * 512 + jn] = v;
        }
    }
}

// ---------------------------------------------------------------------------
extern "C" void kernel_launch(void* const* d_in, const int* in_sizes, int n_in,
                              void* d_out, int out_size, void* d_ws, size_t ws_size,
                              hipStream_t stream) {
    const float* h0     = (const float*)d_in[0];
    const float* ins    = (const float*)d_in[1];
    const int*   resets = (const int*)  d_in[2];
    const float* Wi     = (const float*)d_in[3];
    const float* bi     = (const float*)d_in[4];
    const float* Wh_rz  = (const float*)d_in[5];
    const float* Wh_n   = (const float*)d_in[6];
    const float* bh_n   = (const float*)d_in[7];

    float* out = (float*)d_out;
    float* hT  = out;
    float* ys  = out + (size_t)B_SZ * HD;

    const size_t WPLANE = (size_t)3072 * 512;
    const size_t wbytes = WPLANE * 2 * sizeof(_Float16);   // 6.3 MB

    int CH = 0;
    const int cands[8] = {128, 64, 32, 16, 8, 4, 2, 1};
    for (int c = 0; c < 8; ++c) {
        size_t need = wbytes + (size_t)cands[c] * 512 * 1536 * sizeof(float);
        if (ws_size >= need) { CH = cands[c]; break; }
    }

    if (CH > 0) {
        _Float16* WT_hi = (_Float16*)d_ws;
        _Float16* WT_lo = WT_hi + WPLANE;
        float* gi = (float*)((char*)d_ws + wbytes);
        conv_w<<<dim3(8, 48), 256, 0, stream>>>(Wi, Wh_rz, Wh_n, WT_hi, WT_lo);
        for (int t0 = 0; t0 < T_STEPS; t0 += CH) {
            const int R = CH * 512;
            gi_gemm<<<dim3(24, R / 64), 256, 0, stream>>>(
                ins + (size_t)t0 * 512 * 512, WT_hi, WT_lo, bi, gi);
            for (int t = t0; t < t0 + CH; ++t) {
                const float* hp = (t == 0) ? h0 : (ys + (size_t)(t - 1) * 512 * 512);
                float* ho = ys + (size_t)t * 512 * 512;
                gru_step_h<<<dim3(16, 8), 256, 0, stream>>>(
                    resets + (size_t)t * 512, hp, WT_hi, WT_lo,
                    gi + (size_t)(t - t0) * 512 * 1536,
                    bh_n, ho, (t == T_STEPS - 1) ? hT : nullptr);
            }
        }
    } else {
        dim3 grid(B_SZ / BM_F, HD / BN_F);
        for (int t = 0; t < T_STEPS; ++t) {
            const float* hp = (t == 0) ? h0 : (ys + (size_t)(t - 1) * 512 * 512);
            float* ho = ys + (size_t)t * 512 * 512;
            gru_step_f32<<<grid, 256, 0, stream>>>(
                ins + (size_t)t * 512 * 512, resets + (size_t)t * 512,
                hp, Wi, bi, Wh_rz, Wh_n, bh_n,
                ho, (t == T_STEPS - 1) ? hT : nullptr);
        }
    }
}

// Round 5
// 2584.864 us; speedup vs baseline: 1.5824x; 1.5824x over previous
//
#include <hip/hip_runtime.h>
#include <cmath>

// GRU scan, T=128 B=512 D=H=512, split-f16 MFMA (f32-accurate):
//   v = hi + lo/2048 ; a*b ~= ah*bh + (ah*bl + al*bh)/2048
// Phase 0: transpose+split weights -> WT_hi/WT_lo [3072][512] in d_ws.
// Phase 1: gi = x@Wi + bi (round-3 kernel; grid order n-fastest for L2 reuse).
// Phase 2: 128 step kernels: 32m x 32j x 3gates tiles, grid(16,16)=256 blocks,
//   h staged once in LDS (one barrier), weights direct-from-global 2-deep
//   prefetch, epilogue operands prefetched before K-loop.
// d_out = [hT (B*H) | ys (T*B*H)]; h_prev for step t read from ys[t-1].

#define T_STEPS 128
#define B_SZ 512
#define HD 512

typedef __attribute__((ext_vector_type(8))) _Float16 f16x8;
typedef __attribute__((ext_vector_type(4))) float f32x4;

#define MFMA16(a, b, c) __builtin_amdgcn_mfma_f32_16x16x32_f16((a), (b), (c), 0, 0, 0)

__device__ __forceinline__ float sigf_(float x) { return 1.0f / (1.0f + __expf(-x)); }
__device__ __forceinline__ float tanhf_(float x) { return 1.0f - 2.0f / (__expf(2.0f * x) + 1.0f); }

// ---------------------------------------------------------------------------
// Phase 0: transpose + split weights. WT[n][k]: n<1536 -> Wi col n;
// n>=1536: m=n-1536, g=m>>9, c=m&511: g<2 -> Wh_rz[k][g*512+c]; g==2 -> Wh_n[k][c]
// ---------------------------------------------------------------------------
__global__ __launch_bounds__(256) void conv_w(
    const float* __restrict__ Wi, const float* __restrict__ Wh_rz,
    const float* __restrict__ Wh_n,
    _Float16* __restrict__ WT_hi, _Float16* __restrict__ WT_lo)
{
    __shared__ float Tl[64][65];
    const int tid = threadIdx.x;
    const int k0 = blockIdx.x * 64;
    const int n0 = blockIdx.y * 64;

    const float* base;
    int stride;
    if (n0 < 1536) { base = Wi + n0; stride = 1536; }
    else {
        int m = n0 - 1536, g = m >> 9, c = m & 511;
        if (g < 2) { base = Wh_rz + g * 512 + c; stride = 1024; }
        else       { base = Wh_n + c;            stride = 512; }
    }

    #pragma unroll
    for (int p = 0; p < 4; ++p) {
        int kr = p * 16 + (tid >> 4);
        int nc = (tid & 15) * 4;
        float4 v = *(const float4*)(base + (size_t)(k0 + kr) * stride + nc);
        Tl[kr][nc + 0] = v.x; Tl[kr][nc + 1] = v.y;
        Tl[kr][nc + 2] = v.z; Tl[kr][nc + 3] = v.w;
    }
    __syncthreads();

    const int nr  = tid >> 2;
    const int kc0 = (tid & 3) * 16;
    f16x8 h0v, h1v, l0v, l1v;
    #pragma unroll
    for (int j = 0; j < 16; ++j) {
        float v = Tl[kc0 + j][nr];
        _Float16 th = (_Float16)v;
        _Float16 tl = (_Float16)((v - (float)th) * 2048.0f);
        if (j < 8) { h0v[j] = th; l0v[j] = tl; }
        else       { h1v[j - 8] = th; l1v[j - 8] = tl; }
    }
    size_t o = (size_t)(n0 + nr) * 512 + k0 + kc0;
    *(f16x8*)(WT_hi + o)     = h0v;
    *(f16x8*)(WT_hi + o + 8) = h1v;
    *(f16x8*)(WT_lo + o)     = l0v;
    *(f16x8*)(WT_lo + o + 8) = l1v;
}

// ---------------------------------------------------------------------------
// Phase 1: gi = x @ Wi + bi (round-3 structure; n0 from blockIdx.x now).
// BM=128, BN=64, BK=32, 4 waves; register prefetch of next K-stage.
// ---------------------------------------------------------------------------
__global__ __launch_bounds__(256, 1) void gi_gemm(
    const float* __restrict__ x,        // [R][512]
    const _Float16* __restrict__ WT_hi, // rows 0..1535 = Wi cols
    const _Float16* __restrict__ WT_lo,
    const float* __restrict__ bi,       // [1536]
    float* __restrict__ gi)             // [R][1536]
{
    __shared__ _Float16 Ah[128 * 40], Al[128 * 40];
    __shared__ _Float16 Bh[64 * 40],  Bl[64 * 40];

    const int tid = threadIdx.x;
    const int n0 = blockIdx.x * 64;     // n fastest -> x-tile shared, weights L2
    const int m0 = blockIdx.y * 128;
    const int l = tid & 63, w = tid >> 6;
    const int lr = l & 15, lk = (l >> 4) * 8;

    const int ar = tid >> 1;        // 0..127
    const int ac = (tid & 1) * 16;  // 0 / 16
    const int br = tid >> 2;        // 0..63
    const int bc = (tid & 3) * 8;

    const float*    xrow = x + (size_t)(m0 + ar) * 512 + ac;
    const _Float16* bhp  = WT_hi + (size_t)(n0 + br) * 512 + bc;
    const _Float16* blp  = WT_lo + (size_t)(n0 + br) * 512 + bc;

    f32x4 am_[2][4], ac_[2][4];
    #pragma unroll
    for (int i = 0; i < 2; ++i)
        #pragma unroll
        for (int jq = 0; jq < 4; ++jq) {
            am_[i][jq] = (f32x4){0, 0, 0, 0};
            ac_[i][jq] = (f32x4){0, 0, 0, 0};
        }

    float4 xv0 = *(const float4*)(xrow + 0);
    float4 xv1 = *(const float4*)(xrow + 4);
    float4 xv2 = *(const float4*)(xrow + 8);
    float4 xv3 = *(const float4*)(xrow + 12);
    f16x8 bhv = *(const f16x8*)bhp;
    f16x8 blv = *(const f16x8*)blp;

    for (int s = 0; s < 16; ++s) {
        __syncthreads();
        {
            float xf[16] = {xv0.x, xv0.y, xv0.z, xv0.w, xv1.x, xv1.y, xv1.z, xv1.w,
                            xv2.x, xv2.y, xv2.z, xv2.w, xv3.x, xv3.y, xv3.z, xv3.w};
            f16x8 hh0, hl0, hh1, hl1;
            #pragma unroll
            for (int j = 0; j < 8; ++j) {
                float v = xf[j];
                _Float16 th = (_Float16)v;
                hh0[j] = th; hl0[j] = (_Float16)((v - (float)th) * 2048.0f);
                v = xf[j + 8];
                th = (_Float16)v;
                hh1[j] = th; hl1[j] = (_Float16)((v - (float)th) * 2048.0f);
            }
            *(f16x8*)&Ah[ar * 40 + ac]     = hh0;
            *(f16x8*)&Al[ar * 40 + ac]     = hl0;
            *(f16x8*)&Ah[ar * 40 + ac + 8] = hh1;
            *(f16x8*)&Al[ar * 40 + ac + 8] = hl1;
            *(f16x8*)&Bh[br * 40 + bc] = bhv;
            *(f16x8*)&Bl[br * 40 + bc] = blv;
        }
        __syncthreads();
        if (s < 15) {
            const int k0 = (s + 1) * 32;
            xv0 = *(const float4*)(xrow + k0 + 0);
            xv1 = *(const float4*)(xrow + k0 + 4);
            xv2 = *(const float4*)(xrow + k0 + 8);
            xv3 = *(const float4*)(xrow + k0 + 12);
            bhv = *(const f16x8*)(bhp + k0);
            blv = *(const f16x8*)(blp + k0);
        }
        f16x8 ah[2], al[2], bhf[4], blf[4];
        #pragma unroll
        for (int fm = 0; fm < 2; ++fm) {
            ah[fm] = *(const f16x8*)&Ah[(w * 32 + fm * 16 + lr) * 40 + lk];
            al[fm] = *(const f16x8*)&Al[(w * 32 + fm * 16 + lr) * 40 + lk];
        }
        #pragma unroll
        for (int fn = 0; fn < 4; ++fn) {
            bhf[fn] = *(const f16x8*)&Bh[(fn * 16 + lr) * 40 + lk];
            blf[fn] = *(const f16x8*)&Bl[(fn * 16 + lr) * 40 + lk];
        }
        #pragma unroll
        for (int fm = 0; fm < 2; ++fm)
            #pragma unroll
            for (int fn = 0; fn < 4; ++fn) {
                am_[fm][fn] = MFMA16(ah[fm], bhf[fn], am_[fm][fn]);
                ac_[fm][fn] = MFMA16(ah[fm], blf[fn], ac_[fm][fn]);
                ac_[fm][fn] = MFMA16(al[fm], bhf[fn], ac_[fm][fn]);
            }
    }

    const float inv = 1.0f / 2048.0f;
    #pragma unroll
    for (int fn = 0; fn < 4; ++fn) {
        const int col = n0 + fn * 16 + lr;
        const float bv = bi[col];
        #pragma unroll
        for (int fm = 0; fm < 2; ++fm)
            #pragma unroll
            for (int i = 0; i < 4; ++i) {
                int row = m0 + w * 32 + fm * 16 + (l >> 4) * 4 + i;
                gi[(size_t)row * 1536 + col] =
                    am_[fm][fn][i] + ac_[fm][fn][i] * inv + bv;
            }
    }
}

// ---------------------------------------------------------------------------
// Phase 2: step kernel. Tile 32m x 32j x 3 gates. grid (16 j, 16 m) = 256 blocks.
// 4 waves: (mh = w>>1, jh = w&1) -> wave tile 16m x 16j.
// h staged once in LDS (split f16, stride 520); weights direct from global,
// 2-deep register prefetch; ONE barrier; epilogue operands prefetched.
// ---------------------------------------------------------------------------
__global__ __launch_bounds__(256, 1) void gru_step_h(
    const int*   __restrict__ rst,      // [B]
    const float* __restrict__ hsrc,     // [B][512]
    const _Float16* __restrict__ WT_hi, // hidden rows at 1536+
    const _Float16* __restrict__ WT_lo,
    const float* __restrict__ gi_t,     // [512][1536] (bi folded in)
    const float* __restrict__ bh_n,     // [512]
    float* __restrict__ hdst,
    float* __restrict__ hT_out)
{
    __shared__ __align__(16) _Float16 Ah[32 * 520];
    __shared__ __align__(16) _Float16 Al[32 * 520];

    const int tid = threadIdx.x;
    const int j0 = blockIdx.x * 32;
    const int m0 = blockIdx.y * 32;
    const int l = tid & 63, w = tid >> 6;
    const int mh = w >> 1, jh = w & 1;
    const int lr = l & 15, lkq = l >> 4, lk = lkq * 8;
    const int j = j0 + jh * 16 + lr;    // this lane's output column

    // ---- prefetch epilogue operands (hide under GEMM) ----
    float gi_pre[3][4], h_pre[4];
    #pragma unroll
    for (int i = 0; i < 4; ++i) {
        const int row = m0 + mh * 16 + lkq * 4 + i;
        const size_t gb = (size_t)row * 1536 + j;
        gi_pre[0][i] = gi_t[gb];
        gi_pre[1][i] = gi_t[gb + 512];
        gi_pre[2][i] = gi_t[gb + 1024];
        h_pre[i] = hsrc[(size_t)row * 512 + j];
    }

    // ---- stage h rows m0..m0+31 (f32 -> split f16, reset-masked) ----
    {
        const int srow  = tid >> 3;        // 0..31
        const int scol0 = (tid & 7) * 8;
        const bool smask = (rst[m0 + srow] != 0);
        const float* hp = hsrc + (size_t)(m0 + srow) * 512;
        #pragma unroll
        for (int c = 0; c < 8; ++c) {
            const int col = c * 64 + scol0;
            float4 v0 = *(const float4*)(hp + col);
            float4 v1 = *(const float4*)(hp + col + 4);
            if (smask) { v0 = make_float4(0,0,0,0); v1 = make_float4(0,0,0,0); }
            float f[8] = {v0.x, v0.y, v0.z, v0.w, v1.x, v1.y, v1.z, v1.w};
            f16x8 hh, ll;
            #pragma unroll
            for (int q = 0; q < 8; ++q) {
                float v = f[q];
                _Float16 th = (_Float16)v;
                hh[q] = th; ll[q] = (_Float16)((v - (float)th) * 2048.0f);
            }
            *(f16x8*)&Ah[srow * 520 + col] = hh;
            *(f16x8*)&Al[srow * 520 + col] = ll;
        }
    }
    __syncthreads();

    // ---- B streams (direct global, K-major rows), 2-deep prefetch ----
    const _Float16* bh_p = WT_hi + (size_t)(1536 + j) * 512 + lk;
    const _Float16* bl_p = WT_lo + (size_t)(1536 + j) * 512 + lk;
    constexpr size_t GS = (size_t)512 * 512;   // gate stride

    f32x4 am[3], ac[3];
    #pragma unroll
    for (int g = 0; g < 3; ++g) { am[g] = (f32x4){0,0,0,0}; ac[g] = (f32x4){0,0,0,0}; }

    f16x8 cur[6], nxt[6];
    cur[0] = *(const f16x8*)(bh_p);
    cur[1] = *(const f16x8*)(bh_p + GS);
    cur[2] = *(const f16x8*)(bh_p + 2 * GS);
    cur[3] = *(const f16x8*)(bl_p);
    cur[4] = *(const f16x8*)(bl_p + GS);
    cur[5] = *(const f16x8*)(bl_p + 2 * GS);
    nxt[0] = *(const f16x8*)(bh_p + 32);
    nxt[1] = *(const f16x8*)(bh_p + GS + 32);
    nxt[2] = *(const f16x8*)(bh_p + 2 * GS + 32);
    nxt[3] = *(const f16x8*)(bl_p + 32);
    nxt[4] = *(const f16x8*)(bl_p + GS + 32);
    nxt[5] = *(const f16x8*)(bl_p + 2 * GS + 32);

    const int abase = (mh * 16 + lr) * 520 + lk;
    #pragma unroll
    for (int kk = 0; kk < 16; ++kk) {
        f16x8 tmp[6];
        if (kk < 14) {
            const int o = (kk + 2) * 32;
            tmp[0] = *(const f16x8*)(bh_p + o);
            tmp[1] = *(const f16x8*)(bh_p + GS + o);
            tmp[2] = *(const f16x8*)(bh_p + 2 * GS + o);
            tmp[3] = *(const f16x8*)(bl_p + o);
            tmp[4] = *(const f16x8*)(bl_p + GS + o);
            tmp[5] = *(const f16x8*)(bl_p + 2 * GS + o);
        } else {
            #pragma unroll
            for (int q = 0; q < 6; ++q) tmp[q] = cur[q];
        }
        f16x8 ah = *(const f16x8*)&Ah[abase + kk * 32];
        f16x8 al = *(const f16x8*)&Al[abase + kk * 32];
        am[0] = MFMA16(ah, cur[0], am[0]);
        ac[0] = MFMA16(ah, cur[3], ac[0]);
        ac[0] = MFMA16(al, cur[0], ac[0]);
        am[1] = MFMA16(ah, cur[1], am[1]);
        ac[1] = MFMA16(ah, cur[4], ac[1]);
        ac[1] = MFMA16(al, cur[1], ac[1]);
        am[2] = MFMA16(ah, cur[2], am[2]);
        ac[2] = MFMA16(ah, cur[5], ac[2]);
        ac[2] = MFMA16(al, cur[2], ac[2]);
        #pragma unroll
        for (int q = 0; q < 6; ++q) { cur[q] = nxt[q]; nxt[q] = tmp[q]; }
    }

    // ---- epilogue: gates ----
    const float bhn = bh_n[j];
    const float inv = 1.0f / 2048.0f;
    const int rowb = m0 + mh * 16 + lkq * 4;
    #pragma unroll
    for (int i = 0; i < 4; ++i) {
        const int row = rowb + i;
        const bool rm = (rst[row] != 0);
        const float heff = rm ? 0.f : h_pre[i];
        const float r = sigf_(gi_pre[0][i] + am[0][i] + ac[0][i] * inv);
        const float z = sigf_(gi_pre[1][i] + am[1][i] + ac[1][i] * inv);
        const float n = tanhf_(gi_pre[2][i] + r * (am[2][i] + ac[2][i] * inv + bhn));
        const float hv = (1.f - z) * n + z * heff;
        hdst[(size_t)row * 512 + j] = hv;
        if (hT_out) hT_out[(size_t)row * 512 + j] = hv;
    }
}

// ---------------------------------------------------------------------------
// Fallback: pure-f32 step kernel (only if d_ws too small).
// ---------------------------------------------------------------------------
constexpr int BM_F = 32, BN_F = 32, BK_F = 32;
constexpr int LDT = BM_F + 4;

__global__ __launch_bounds__(256, 1) void gru_step_f32(
    const float* __restrict__ x, const int* __restrict__ rst,
    const float* __restrict__ h_prev, const float* __restrict__ Wi,
    const float* __restrict__ bi, const float* __restrict__ Wh_rz,
    const float* __restrict__ Wh_n, const float* __restrict__ bh_n,
    float* __restrict__ h_out, float* __restrict__ hT_out)
{
    __shared__ float xs[BK_F][LDT];
    __shared__ float hs[BK_F][LDT];
    __shared__ float wt[6][BK_F][LDT];

    const int tid = threadIdx.x;
    const int bm0 = blockIdx.x * BM_F;
    const int jn0 = blockIdx.y * BN_F;
    const int lrw = tid >> 3;
    const int lcw = (tid & 7) << 2;
    const int ty = tid >> 4, tx = tid & 15;
    const int row0 = 2 * ty, col0 = 2 * tx;

    float aR[2][2] = {{0,0},{0,0}}, aZ[2][2] = {{0,0},{0,0}}, aN[2][2] = {{0,0},{0,0}};
    float hR[2][2] = {{0,0},{0,0}}, hZ[2][2] = {{0,0},{0,0}}, hN[2][2] = {{0,0},{0,0}};

    const int ldrow = bm0 + lrw;
    const bool rmaskld = (rst[ldrow] != 0);
    const float* xrow = x + (size_t)ldrow * 512;
    const float* hrow = h_prev + (size_t)ldrow * 512;

    for (int k0 = 0; k0 < 512; k0 += BK_F) {
        float4 xv = *(const float4*)(xrow + k0 + lcw);
        float4 hv = *(const float4*)(hrow + k0 + lcw);
        if (rmaskld) { hv.x = hv.y = hv.z = hv.w = 0.f; }
        const float* wi_row = Wi + (size_t)(k0 + lrw) * 1536;
        const float* wh_row = Wh_rz + (size_t)(k0 + lrw) * 1024;
        float4 w0v = *(const float4*)(wi_row + jn0 + lcw);
        float4 w1v = *(const float4*)(wi_row + 512 + jn0 + lcw);
        float4 w2v = *(const float4*)(wi_row + 1024 + jn0 + lcw);
        float4 w3v = *(const float4*)(wh_row + jn0 + lcw);
        float4 w4v = *(const float4*)(wh_row + 512 + jn0 + lcw);
        float4 w5v = *(const float4*)(Wh_n + (size_t)(k0 + lrw) * 512 + jn0 + lcw);
        __syncthreads();
        xs[lcw+0][lrw]=xv.x; xs[lcw+1][lrw]=xv.y; xs[lcw+2][lrw]=xv.z; xs[lcw+3][lrw]=xv.w;
        hs[lcw+0][lrw]=hv.x; hs[lcw+1][lrw]=hv.y; hs[lcw+2][lrw]=hv.z; hs[lcw+3][lrw]=hv.w;
        *(float4*)&wt[0][lrw][lcw] = w0v; *(float4*)&wt[1][lrw][lcw] = w1v;
        *(float4*)&wt[2][lrw][lcw] = w2v; *(float4*)&wt[3][lrw][lcw] = w3v;
        *(float4*)&wt[4][lrw][lcw] = w4v; *(float4*)&wt[5][lrw][lcw] = w5v;
        __syncthreads();
        #pragma unroll
        for (int kk = 0; kk < BK_F; ++kk) {
            float2 xa = *(const float2*)&xs[kk][row0];
            float2 ha = *(const float2*)&hs[kk][row0];
            float2 w0 = *(const float2*)&wt[0][kk][col0];
            float2 w1 = *(const float2*)&wt[1][kk][col0];
            float2 w2 = *(const float2*)&wt[2][kk][col0];
            float2 w3 = *(const float2*)&wt[3][kk][col0];
            float2 w4 = *(const float2*)&wt[4][kk][col0];
            float2 w5 = *(const float2*)&wt[5][kk][col0];
            aR[0][0]=fmaf(xa.x,w0.x,aR[0][0]); aR[0][1]=fmaf(xa.x,w0.y,aR[0][1]);
            aR[1][0]=fmaf(xa.y,w0.x,aR[1][0]); aR[1][1]=fmaf(xa.y,w0.y,aR[1][1]);
            aZ[0][0]=fmaf(xa.x,w1.x,aZ[0][0]); aZ[0][1]=fmaf(xa.x,w1.y,aZ[0][1]);
            aZ[1][0]=fmaf(xa.y,w1.x,aZ[1][0]); aZ[1][1]=fmaf(xa.y,w1.y,aZ[1][1]);
            aN[0][0]=fmaf(xa.x,w2.x,aN[0][0]); aN[0][1]=fmaf(xa.x,w2.y,aN[0][1]);
            aN[1][0]=fmaf(xa.y,w2.x,aN[1][0]); aN[1][1]=fmaf(xa.y,w2.y,aN[1][1]);
            hR[0][0]=fmaf(ha.x,w3.x,hR[0][0]); hR[0][1]=fmaf(ha.x,w3.y,hR[0][1]);
            hR[1][0]=fmaf(ha.y,w3.x,hR[1][0]); hR[1][1]=fmaf(ha.y,w3.y,hR[1][1]);
            hZ[0][0]=fmaf(ha.x,w4.x,hZ[0][0]); hZ[0][1]=fmaf(ha.x,w4.y,hZ[0][1]);
            hZ[1][0]=fmaf(ha.y,w4.x,hZ[1][0]); hZ[1][1]=fmaf(ha.y,w4.y,hZ[1][1]);
            hN[0][0]=fmaf(ha.x,w5.x,hN[0][0]); hN[0][1]=fmaf(ha.x,w5.y,hN[0][1]);
            hN[1][0]=fmaf(ha.y,w5.x,hN[1][0]); hN[1][1]=fmaf(ha.y,w5.y,hN[1][1]);
        }
    }
    #pragma unroll
    for (int ii = 0; ii < 2; ++ii) {
        const int b = bm0 + row0 + ii;
        const bool rm = (rst[b] != 0);
        #pragma unroll
        for (int jj = 0; jj < 2; ++jj) {
            const int jn = jn0 + col0 + jj;
            const float heff = rm ? 0.f : h_prev[(size_t)b * 512 + jn];
            const float r = sigf_(aR[ii][jj] + bi[jn] + hR[ii][jj]);
            const float z = sigf_(aZ[ii][jj] + bi[512 + jn] + hZ[ii][jj]);
            const float n = tanhf(aN[ii][jj] + bi[1024 + jn] + r * (hN[ii][jj] + bh_n[jn]));
            const float v = (1.f - z) * n + z * heff;
            h_out[(size_t)b * 512 + jn] = v;
            if (hT_out) hT_out[(size_t)b * 512 + jn] = v;
        }
    }
}

// ---------------------------------------------------------------------------
extern "C" void kernel_launch(void* const* d_in, const int* in_sizes, int n_in,
                              void* d_out, int out_size, void* d_ws, size_t ws_size,
                              hipStream_t stream) {
    const float* h0     = (const float*)d_in[0];
    const float* ins    = (const float*)d_in[1];
    const int*   resets = (const int*)  d_in[2];
    const float* Wi     = (const float*)d_in[3];
    const float* bi     = (const float*)d_in[4];
    const float* Wh_rz  = (const float*)d_in[5];
    const float* Wh_n   = (const float*)d_in[6];
    const float* bh_n   = (const float*)d_in[7];

    float* out = (float*)d_out;
    float* hT  = out;
    float* ys  = out + (size_t)B_SZ * HD;

    const size_t WPLANE = (size_t)3072 * 512;
    const size_t wbytes = WPLANE * 2 * sizeof(_Float16);   // 6.3 MB

    int CH = 0;
    const int cands[8] = {128, 64, 32, 16, 8, 4, 2, 1};
    for (int c = 0; c < 8; ++c) {
        size_t need = wbytes + (size_t)cands[c] * 512 * 1536 * sizeof(float);
        if (ws_size >= need) { CH = cands[c]; break; }
    }

    if (CH > 0) {
        _Float16* WT_hi = (_Float16*)d_ws;
        _Float16* WT_lo = WT_hi + WPLANE;
        float* gi = (float*)((char*)d_ws + wbytes);
        conv_w<<<dim3(8, 48), 256, 0, stream>>>(Wi, Wh_rz, Wh_n, WT_hi, WT_lo);
        for (int t0 = 0; t0 < T_STEPS; t0 += CH) {
            const int R = CH * 512;
            gi_gemm<<<dim3(24, R / 128), 256, 0, stream>>>(
                ins + (size_t)t0 * 512 * 512, WT_hi, WT_lo, bi, gi);
            for (int t = t0; t < t0 + CH; ++t) {
                const float* hp = (t == 0) ? h0 : (ys + (size_t)(t - 1) * 512 * 512);
                float* ho = ys + (size_t)t * 512 * 512;
                gru_step_h<<<dim3(16, 16), 256, 0, stream>>>(
                    resets + (size_t)t * 512, hp, WT_hi, WT_lo,
                    gi + (size_t)(t - t0) * 512 * 1536,
                    bh_n, ho, (t == T_STEPS - 1) ? hT : nullptr);
            }
        }
    } else {
        dim3 grid(B_SZ / BM_F, HD / BN_F);
        for (int t = 0; t < T_STEPS; ++t) {
            const float* hp = (t == 0) ? h0 : (ys + (size_t)(t - 1) * 512 * 512);
            float* ho = ys + (size_t)t * 512 * 512;
            gru_step_f32<<<grid, 256, 0, stream>>>(
                ins + (size_t)t * 512 * 512, resets + (size_t)t * 512,
                hp, Wi, bi, Wh_rz, Wh_n, bh_n,
                ho, (t == T_STEPS - 1) ? hT : nullptr);
        }
    }
}